// Round 3
// baseline (748.540 us; speedup 1.0000x reference)
//
#include <hip/hip_runtime.h>

#define ND 32
#define ED 8
#define NL 4
#define NG 1000
#define SCAN_B 512

// ---------- init ----------

__global__ void k_init_h(const float* __restrict__ x,
                         const float* __restrict__ W,  // [2][ND]
                         const float* __restrict__ b,  // [ND]
                         float* __restrict__ h, int N) {
  int i = blockIdx.x * blockDim.x + threadIdx.x;
  if (i >= N * ND) return;
  int n = i >> 5, d = i & (ND - 1);
  h[i] = fmaf(x[2 * n], W[d], fmaf(x[2 * n + 1], W[ND + d], b[d]));
}

// ---------- CSR build (counting sort by dst) ----------

__global__ void k_hist(const int* __restrict__ dst, int* __restrict__ cnt, int E) {
  int i = blockIdx.x * blockDim.x + threadIdx.x;
  if (i < E) atomicAdd(&cnt[dst[i]], 1);
}

__global__ void k_blocksum(const int* __restrict__ cnt, int* __restrict__ bsum, int N) {
  __shared__ int s[SCAN_B];
  int i = blockIdx.x * SCAN_B + threadIdx.x;
  s[threadIdx.x] = (i < N) ? cnt[i] : 0;
  __syncthreads();
  for (int st = SCAN_B / 2; st > 0; st >>= 1) {
    if (threadIdx.x < (unsigned)st) s[threadIdx.x] += s[threadIdx.x + st];
    __syncthreads();
  }
  if (threadIdx.x == 0) bsum[blockIdx.x] = s[0];
}

__global__ void k_scan_bsums(int* __restrict__ bsum, int nb,
                             int* __restrict__ offsets, int N) {
  __shared__ int s[1024];
  __shared__ int tot;
  int tid = threadIdx.x;
  if (nb <= 1024) {
    for (int i = tid; i < nb; i += blockDim.x) s[i] = bsum[i];
    __syncthreads();
    if (tid == 0) {
      int run = 0;
      for (int i = 0; i < nb; ++i) { int v = s[i]; s[i] = run; run += v; }
      tot = run;
    }
    __syncthreads();
    for (int i = tid; i < nb; i += blockDim.x) bsum[i] = s[i];
    if (tid == 0) offsets[N] = tot;
  } else if (tid == 0) {
    int run = 0;
    for (int i = 0; i < nb; ++i) { int v = bsum[i]; bsum[i] = run; run += v; }
    offsets[N] = run;
  }
}

__global__ void k_scan_local(const int* __restrict__ cnt,
                             const int* __restrict__ bsum,
                             int* __restrict__ offsets, int N) {
  __shared__ int s[SCAN_B];
  int i = blockIdx.x * SCAN_B + threadIdx.x;
  int v = (i < N) ? cnt[i] : 0;
  s[threadIdx.x] = v;
  __syncthreads();
  for (int st = 1; st < SCAN_B; st <<= 1) {
    int t = (threadIdx.x >= (unsigned)st) ? s[threadIdx.x - st] : 0;
    __syncthreads();
    s[threadIdx.x] += t;
    __syncthreads();
  }
  if (i < N) offsets[i] = bsum[blockIdx.x] + s[threadIdx.x] - v;  // exclusive
}

// scatter only a 4-byte index: perm[pos] = original edge id
__global__ void k_perm(const int* __restrict__ dst,
                       const int* __restrict__ offsets, int* __restrict__ cursor,
                       int* __restrict__ perm, int E) {
  int i = blockIdx.x * blockDim.x + threadIdx.x;
  if (i >= E) return;
  int d = dst[i];
  int pos = offsets[d] + atomicAdd(&cursor[d], 1);
  perm[pos] = i;
}

// coalesced build of sorted arrays: gather reads (L2-absorbed), coalesced writes
__global__ void k_gather(const int* __restrict__ perm,
                         const int* __restrict__ src, const int* __restrict__ dst,
                         const float* __restrict__ ea,
                         const float* __restrict__ We,  // [ED]
                         const float* __restrict__ be,  // [ED]
                         int* __restrict__ ssrc, int* __restrict__ sdst,
                         float* __restrict__ e, int E) {
  __shared__ float sW[ED], sb[ED];
  if (threadIdx.x < ED) { sW[threadIdx.x] = We[threadIdx.x]; sb[threadIdx.x] = be[threadIdx.x]; }
  __syncthreads();
  int p = blockIdx.x * blockDim.x + threadIdx.x;
  if (p >= E) return;
  int i = perm[p];
  ssrc[p] = src[i];
  sdst[p] = dst[i];
  float a = ea[i];
  float4 v0, v1;
  v0.x = fmaf(a, sW[0], sb[0]); v0.y = fmaf(a, sW[1], sb[1]);
  v0.z = fmaf(a, sW[2], sb[2]); v0.w = fmaf(a, sW[3], sb[3]);
  v1.x = fmaf(a, sW[4], sb[4]); v1.y = fmaf(a, sW[5], sb[5]);
  v1.z = fmaf(a, sW[6], sb[6]); v1.w = fmaf(a, sW[7], sb[7]);
  float4* e4 = reinterpret_cast<float4*>(e + (size_t)p * ED);
  e4[0] = v0; e4[1] = v1;
}

// ---------- layer kernels ----------

__device__ __forceinline__ void acc4_ed(float4 v, const float* __restrict__ w,
                                        float* acc) {
#pragma unroll
  for (int j = 0; j < ED; ++j) acc[j] = fmaf(v.x, w[j], acc[j]);
#pragma unroll
  for (int j = 0; j < ED; ++j) acc[j] = fmaf(v.y, w[ED + j], acc[j]);
#pragma unroll
  for (int j = 0; j < ED; ++j) acc[j] = fmaf(v.z, w[2 * ED + j], acc[j]);
#pragma unroll
  for (int j = 0; j < ED; ++j) acc[j] = fmaf(v.w, w[3 * ED + j], acc[j]);
}

__device__ __forceinline__ void acc4_nd(float4 v, const float* __restrict__ w,
                                        float* acc) {
#pragma unroll
  for (int j = 0; j < ND; ++j) acc[j] = fmaf(v.x, w[j], acc[j]);
#pragma unroll
  for (int j = 0; j < ND; ++j) acc[j] = fmaf(v.y, w[ND + j], acc[j]);
#pragma unroll
  for (int j = 0; j < ND; ++j) acc[j] = fmaf(v.z, w[2 * ND + j], acc[j]);
#pragma unroll
  for (int j = 0; j < ND; ++j) acc[j] = fmaf(v.w, w[3 * ND + j], acc[j]);
}

// edge MLP + fused segment-sum into agg (dst-sorted edges, wave-segmented scan)
__global__ void k_edge(const float* __restrict__ h,
                       float* __restrict__ e,
                       const int* __restrict__ ssrc,
                       const int* __restrict__ sdst,
                       const float* __restrict__ W,  // [(2*ND+ED)][ED]
                       const float* __restrict__ b,  // [ED]
                       float* __restrict__ agg,      // [N][ED], pre-zeroed
                       int E) {
  __shared__ float sW[(2 * ND + ED) * ED];
  __shared__ float sb[ED];
  for (int i = threadIdx.x; i < (2 * ND + ED) * ED; i += blockDim.x) sW[i] = W[i];
  if (threadIdx.x < ED) sb[threadIdx.x] = b[threadIdx.x];
  __syncthreads();
  int i = blockIdx.x * blockDim.x + threadIdx.x;
  int lane = threadIdx.x & 63;
  bool valid = i < E;
  int d = -1;
  float acc[ED];
  if (valid) {
    int s = ssrc[i];
    d = sdst[i];
#pragma unroll
    for (int j = 0; j < ED; ++j) acc[j] = sb[j];
    const float4* hs4 = reinterpret_cast<const float4*>(h + (size_t)s * ND);
    const float4* hd4 = reinterpret_cast<const float4*>(h + (size_t)d * ND);
#pragma unroll
    for (int q = 0; q < ND / 4; ++q) acc4_ed(hs4[q], &sW[q * 4 * ED], acc);
#pragma unroll
    for (int q = 0; q < ND / 4; ++q) acc4_ed(hd4[q], &sW[(ND + q * 4) * ED], acc);
    float4* e4 = reinterpret_cast<float4*>(e + (size_t)i * ED);
    float4 e0 = e4[0], e1 = e4[1];
    acc4_ed(e0, &sW[2 * ND * ED], acc);
    acc4_ed(e1, &sW[(2 * ND + 4) * ED], acc);
#pragma unroll
    for (int j = 0; j < ED; ++j) acc[j] = fmaxf(acc[j], 0.0f);
    // residual e += new_e (uses per-edge new_e, before the scan mutates acc)
    e4[0] = make_float4(e0.x + acc[0], e0.y + acc[1], e0.z + acc[2], e0.w + acc[3]);
    e4[1] = make_float4(e1.x + acc[4], e1.y + acc[5], e1.z + acc[6], e1.w + acc[7]);
  } else {
#pragma unroll
    for (int j = 0; j < ED; ++j) acc[j] = 0.0f;
  }
  // wave-level segmented inclusive scan by dst (dst is sorted => segments contiguous)
#pragma unroll
  for (int off = 1; off < 64; off <<= 1) {
    int dup = __shfl_up(d, off, 64);
    bool same = (lane >= off) && (dup == d);
#pragma unroll
    for (int j = 0; j < ED; ++j) {
      float v = __shfl_up(acc[j], off, 64);
      if (same) acc[j] += v;
    }
  }
  int dn = __shfl_down(d, 1, 64);
  bool tail = (lane == 63) || (dn != d);
  if (valid && tail) {
    float* ag = agg + (size_t)d * ED;
#pragma unroll
    for (int j = 0; j < ED; ++j) atomicAdd(&ag[j], acc[j]);
  }
}

// node MLP: h += relu([h, agg] @ W + b)
__global__ void k_node(float* __restrict__ h,
                       const float* __restrict__ agg,
                       const float* __restrict__ W,  // [(ND+ED)][ND]
                       const float* __restrict__ b,  // [ND]
                       int N) {
  __shared__ float sW[(ND + ED) * ND];
  __shared__ float sb[ND];
  for (int i = threadIdx.x; i < (ND + ED) * ND; i += blockDim.x) sW[i] = W[i];
  if (threadIdx.x < ND) sb[threadIdx.x] = b[threadIdx.x];
  __syncthreads();
  int n = blockIdx.x * blockDim.x + threadIdx.x;
  if (n >= N) return;
  float acc[ND];
#pragma unroll
  for (int j = 0; j < ND; ++j) acc[j] = sb[j];
  float4* h4 = reinterpret_cast<float4*>(h + (size_t)n * ND);
  float4 hv[ND / 4];
#pragma unroll
  for (int q = 0; q < ND / 4; ++q) {
    hv[q] = h4[q];
    acc4_nd(hv[q], &sW[q * 4 * ND], acc);
  }
  const float4* a4 = reinterpret_cast<const float4*>(agg + (size_t)n * ED);
#pragma unroll
  for (int q = 0; q < ED / 4; ++q) acc4_nd(a4[q], &sW[(ND + q * 4) * ND], acc);
#pragma unroll
  for (int q = 0; q < ND / 4; ++q) {
    float4 o;
    o.x = hv[q].x + fmaxf(acc[q * 4 + 0], 0.0f);
    o.y = hv[q].y + fmaxf(acc[q * 4 + 1], 0.0f);
    o.z = hv[q].z + fmaxf(acc[q * 4 + 2], 0.0f);
    o.w = hv[q].w + fmaxf(acc[q * 4 + 3], 0.0f);
    h4[q] = o;
  }
}

// ---------- readout ----------

__device__ __forceinline__ unsigned int enc_f32(float f) {
  unsigned int bits = __float_as_uint(f);
  return (bits & 0x80000000u) ? ~bits : (bits | 0x80000000u);
}
__device__ __forceinline__ float dec_f32(unsigned int u) {
  unsigned int bits = (u & 0x80000000u) ? (u ^ 0x80000000u) : ~u;
  return __uint_as_float(bits);
}

__global__ void k_logits(const float* __restrict__ h,
                         const int* __restrict__ cand,
                         const int* __restrict__ batch,
                         const float* __restrict__ Wout,  // [ND]
                         const float* __restrict__ bout,  // [1]
                         float* __restrict__ logits,
                         int* __restrict__ seg,
                         unsigned int* __restrict__ mxu,  // pre-zeroed
                         int NC) {
  __shared__ float sW[ND];
  if (threadIdx.x < ND) sW[threadIdx.x] = Wout[threadIdx.x];
  __syncthreads();
  int c = blockIdx.x * blockDim.x + threadIdx.x;
  if (c >= NC) return;
  int idx = cand[c];
  const float* hr = h + (size_t)idx * ND;
  float acc = bout[0];
#pragma unroll
  for (int k = 0; k < ND; ++k) acc = fmaf(hr[k], sW[k], acc);
  logits[c] = acc;
  int g = batch[idx];
  seg[c] = g;
  atomicMax(&mxu[g], enc_f32(acc));
}

__global__ void k_expsum(float* __restrict__ logits,
                         const int* __restrict__ seg,
                         const unsigned int* __restrict__ mxu,
                         float* __restrict__ sum,  // pre-zeroed
                         int NC) {
  int c = blockIdx.x * blockDim.x + threadIdx.x;
  if (c >= NC) return;
  int g = seg[c];
  float sh = logits[c] - dec_f32(mxu[g]);
  logits[c] = sh;
  atomicAdd(&sum[g], expf(sh));
}

__global__ void k_final(const float* __restrict__ shifted,
                        const int* __restrict__ seg,
                        const float* __restrict__ sum,
                        float* __restrict__ out, int NC) {
  int c = blockIdx.x * blockDim.x + threadIdx.x;
  if (c >= NC) return;
  out[c] = shifted[c] - logf(sum[seg[c]]);
}

// ---------- launch ----------

extern "C" void kernel_launch(void* const* d_in, const int* in_sizes, int n_in,
                              void* d_out, int out_size, void* d_ws, size_t ws_size,
                              hipStream_t stream) {
  const float* x       = (const float*)d_in[0];
  const float* ea      = (const float*)d_in[1];
  const float* Wn_in   = (const float*)d_in[2];
  const float* bn_in   = (const float*)d_in[3];
  const float* We_in   = (const float*)d_in[4];
  const float* be_in   = (const float*)d_in[5];
  const float* We_l    = (const float*)d_in[6];
  const float* be_l    = (const float*)d_in[7];
  const float* Wn_l    = (const float*)d_in[8];
  const float* bn_l    = (const float*)d_in[9];
  const float* Wout    = (const float*)d_in[10];
  const float* bout    = (const float*)d_in[11];
  const int* edge_index= (const int*)d_in[12];
  const int* batch     = (const int*)d_in[13];
  const int* cand      = (const int*)d_in[14];

  const int N  = in_sizes[13];
  const int E  = in_sizes[1];
  const int NC = in_sizes[14];
  const int nb = (N + SCAN_B - 1) / SCAN_B;

  char* ws = (char*)d_ws;
  float* h      = (float*)ws; ws += (size_t)N * ND * sizeof(float);
  float* e      = (float*)ws; ws += (size_t)E * ED * sizeof(float);
  float* agg    = (float*)ws; ws += (size_t)N * ED * sizeof(float);
  int*   perm   = (int*)ws;   ws += (size_t)E * sizeof(int);
  int*   ssrc   = (int*)ws;   ws += (size_t)E * sizeof(int);
  int*   sdst   = (int*)ws;   ws += (size_t)E * sizeof(int);
  int*   cnt    = (int*)ws;   ws += (size_t)N * sizeof(int);
  int*   cursor = (int*)ws;   ws += (size_t)N * sizeof(int);
  int*   offs   = (int*)ws;   ws += ((size_t)N + 4) * sizeof(int);
  int*   bsum   = (int*)ws;   ws += 4096;
  float* logits = (float*)ws; ws += (size_t)NC * sizeof(float);
  int*   seg    = (int*)ws;   ws += (size_t)NC * sizeof(int);
  unsigned int* mxu = (unsigned int*)ws; ws += (size_t)NG * sizeof(unsigned int);
  float* sum    = (float*)ws; ws += (size_t)NG * sizeof(float);

  const int* srcp = edge_index;
  const int* dstp = edge_index + E;
  const int blk = 256;

  // CSR build: hist -> scan -> scatter index -> coalesced gather
  hipMemsetAsync(cnt, 0, (size_t)N * sizeof(int), stream);
  hipMemsetAsync(cursor, 0, (size_t)N * sizeof(int), stream);
  k_hist<<<(E + blk - 1) / blk, blk, 0, stream>>>(dstp, cnt, E);
  k_blocksum<<<nb, SCAN_B, 0, stream>>>(cnt, bsum, N);
  k_scan_bsums<<<1, 1024, 0, stream>>>(bsum, nb, offs, N);
  k_scan_local<<<nb, SCAN_B, 0, stream>>>(cnt, bsum, offs, N);
  k_perm<<<(E + blk - 1) / blk, blk, 0, stream>>>(dstp, offs, cursor, perm, E);
  k_gather<<<(E + blk - 1) / blk, blk, 0, stream>>>(
      perm, srcp, dstp, ea, We_in, be_in, ssrc, sdst, e, E);

  k_init_h<<<(N * ND + blk - 1) / blk, blk, 0, stream>>>(x, Wn_in, bn_in, h, N);

  for (int l = 0; l < NL; ++l) {
    hipMemsetAsync(agg, 0, (size_t)N * ED * sizeof(float), stream);
    k_edge<<<(E + blk - 1) / blk, blk, 0, stream>>>(
        h, e, ssrc, sdst, We_l + (size_t)l * (2 * ND + ED) * ED,
        be_l + (size_t)l * ED, agg, E);
    k_node<<<(N + blk - 1) / blk, blk, 0, stream>>>(
        h, agg, Wn_l + (size_t)l * (ND + ED) * ND, bn_l + (size_t)l * ND, N);
  }

  hipMemsetAsync(mxu, 0, NG * sizeof(unsigned int), stream);
  hipMemsetAsync(sum, 0, NG * sizeof(float), stream);
  k_logits<<<(NC + blk - 1) / blk, blk, 0, stream>>>(h, cand, batch, Wout, bout,
                                                     logits, seg, mxu, NC);
  k_expsum<<<(NC + blk - 1) / blk, blk, 0, stream>>>(logits, seg, mxu, sum, NC);
  k_final<<<(NC + blk - 1) / blk, blk, 0, stream>>>(logits, seg, sum,
                                                    (float*)d_out, NC);
}

// Round 4
// 575.600 us; speedup vs baseline: 1.3005x; 1.3005x over previous
//
#include <hip/hip_runtime.h>

#define ND 32
#define ED 8
#define NL 4
#define NG 1000
#define SCAN_B 512

typedef unsigned short u16;

// ---------- bf16 helpers (storage bf16, compute fp32) ----------

__device__ __forceinline__ u16 f2bf(float f) {
  unsigned u = __float_as_uint(f);
  u += 0x7fffu + ((u >> 16) & 1u);  // round-to-nearest-even
  return (u16)(u >> 16);
}
__device__ __forceinline__ unsigned pack2(float a, float b) {
  return (unsigned)f2bf(a) | ((unsigned)f2bf(b) << 16);
}
__device__ __forceinline__ void cvt8(uint4 p, float* o) {
  o[0] = __uint_as_float(p.x << 16); o[1] = __uint_as_float(p.x & 0xffff0000u);
  o[2] = __uint_as_float(p.y << 16); o[3] = __uint_as_float(p.y & 0xffff0000u);
  o[4] = __uint_as_float(p.z << 16); o[5] = __uint_as_float(p.z & 0xffff0000u);
  o[6] = __uint_as_float(p.w << 16); o[7] = __uint_as_float(p.w & 0xffff0000u);
}

// ---------- init ----------

// h[n][0:32] = x[n]@W + b, stored bf16 (4 uint4 per node, coalesced)
__global__ void k_init_h(const float* __restrict__ x,
                         const float* __restrict__ W,  // [2][ND]
                         const float* __restrict__ b,  // [ND]
                         u16* __restrict__ h, int N) {
  __shared__ float sW[2 * ND], sb[ND];
  for (int i = threadIdx.x; i < 2 * ND; i += blockDim.x) sW[i] = W[i];
  if (threadIdx.x < ND) sb[threadIdx.x] = b[threadIdx.x];
  __syncthreads();
  int n = blockIdx.x * blockDim.x + threadIdx.x;
  if (n >= N) return;
  float x0 = x[2 * n], x1 = x[2 * n + 1];
  float v[ND];
#pragma unroll
  for (int d = 0; d < ND; ++d) v[d] = fmaf(x0, sW[d], fmaf(x1, sW[ND + d], sb[d]));
  uint4* h4 = reinterpret_cast<uint4*>(h + (size_t)n * ND);
#pragma unroll
  for (int q = 0; q < 4; ++q) {
    uint4 o;
    o.x = pack2(v[q * 8 + 0], v[q * 8 + 1]);
    o.y = pack2(v[q * 8 + 2], v[q * 8 + 3]);
    o.z = pack2(v[q * 8 + 4], v[q * 8 + 5]);
    o.w = pack2(v[q * 8 + 6], v[q * 8 + 7]);
    h4[q] = o;
  }
}

// ---------- CSR build (counting sort by dst) ----------

__global__ void k_hist(const int* __restrict__ dst, int* __restrict__ cnt, int E) {
  int i = blockIdx.x * blockDim.x + threadIdx.x;
  if (i < E) atomicAdd(&cnt[dst[i]], 1);
}

__global__ void k_blocksum(const int* __restrict__ cnt, int* __restrict__ bsum, int N) {
  __shared__ int s[SCAN_B];
  int i = blockIdx.x * SCAN_B + threadIdx.x;
  s[threadIdx.x] = (i < N) ? cnt[i] : 0;
  __syncthreads();
  for (int st = SCAN_B / 2; st > 0; st >>= 1) {
    if (threadIdx.x < (unsigned)st) s[threadIdx.x] += s[threadIdx.x + st];
    __syncthreads();
  }
  if (threadIdx.x == 0) bsum[blockIdx.x] = s[0];
}

__global__ void k_scan_bsums(int* __restrict__ bsum, int nb,
                             int* __restrict__ offsets, int N) {
  __shared__ int s[1024];
  __shared__ int tot;
  int tid = threadIdx.x;
  if (nb <= 1024) {
    for (int i = tid; i < nb; i += blockDim.x) s[i] = bsum[i];
    __syncthreads();
    if (tid == 0) {
      int run = 0;
      for (int i = 0; i < nb; ++i) { int v = s[i]; s[i] = run; run += v; }
      tot = run;
    }
    __syncthreads();
    for (int i = tid; i < nb; i += blockDim.x) bsum[i] = s[i];
    if (tid == 0) offsets[N] = tot;
  } else if (tid == 0) {
    int run = 0;
    for (int i = 0; i < nb; ++i) { int v = bsum[i]; bsum[i] = run; run += v; }
    offsets[N] = run;
  }
}

__global__ void k_scan_local(const int* __restrict__ cnt,
                             const int* __restrict__ bsum,
                             int* __restrict__ offsets, int N) {
  __shared__ int s[SCAN_B];
  int i = blockIdx.x * SCAN_B + threadIdx.x;
  int v = (i < N) ? cnt[i] : 0;
  s[threadIdx.x] = v;
  __syncthreads();
  for (int st = 1; st < SCAN_B; st <<= 1) {
    int t = (threadIdx.x >= (unsigned)st) ? s[threadIdx.x - st] : 0;
    __syncthreads();
    s[threadIdx.x] += t;
    __syncthreads();
  }
  if (i < N) offsets[i] = bsum[blockIdx.x] + s[threadIdx.x] - v;  // exclusive
}

// fused scatter: one aligned 16-B record per edge {src, dst, ea_bits, 0}
// -> exactly one sector touched per scattered store
__global__ void k_scatter(const int* __restrict__ src, const int* __restrict__ dst,
                          const float* __restrict__ ea,
                          const int* __restrict__ offsets, int* __restrict__ cursor,
                          int4* __restrict__ sedge, int E) {
  int i = blockIdx.x * blockDim.x + threadIdx.x;
  if (i >= E) return;
  int d = dst[i];
  int pos = offsets[d] + atomicAdd(&cursor[d], 1);
  sedge[pos] = make_int4(src[i], d, __float_as_int(ea[i]), 0);
}

// ---------- layer kernels ----------

__device__ __forceinline__ void acc8(const float* __restrict__ v,
                                     const float* __restrict__ w,  // [8][ED]
                                     float* acc) {
#pragma unroll
  for (int k = 0; k < 8; ++k)
#pragma unroll
    for (int j = 0; j < ED; ++j) acc[j] = fmaf(v[k], w[k * ED + j], acc[j]);
}

// edge MLP + fused segment-sum into agg (dst-sorted edges, wave-segmented scan)
// FIRST: e_in computed on the fly from ea (never materialized); else read e bf16.
template <bool FIRST>
__global__ void k_edge(const u16* __restrict__ h,
                       u16* __restrict__ e,
                       const int4* __restrict__ sedge,
                       const float* __restrict__ W,  // [(2*ND+ED)][ED]
                       const float* __restrict__ b,  // [ED]
                       const float* __restrict__ We0,  // [ED] (FIRST only)
                       const float* __restrict__ be0,  // [ED] (FIRST only)
                       float* __restrict__ agg,        // [N][ED], pre-zeroed
                       int E) {
  __shared__ float sW[(2 * ND + ED) * ED];
  __shared__ float sb[ED], sWe[ED], sbe[ED];
  for (int i = threadIdx.x; i < (2 * ND + ED) * ED; i += blockDim.x) sW[i] = W[i];
  if (threadIdx.x < ED) {
    sb[threadIdx.x] = b[threadIdx.x];
    if (FIRST) {
      sWe[threadIdx.x] = We0[threadIdx.x];
      sbe[threadIdx.x] = be0[threadIdx.x];
    }
  }
  __syncthreads();
  int i = blockIdx.x * blockDim.x + threadIdx.x;
  int lane = threadIdx.x & 63;
  bool valid = i < E;
  int d = -1;
  float acc[ED];
  if (valid) {
    int4 sd = sedge[i];
    int s = sd.x;
    d = sd.y;
#pragma unroll
    for (int j = 0; j < ED; ++j) acc[j] = sb[j];
    const uint4* hs4 = reinterpret_cast<const uint4*>(h + (size_t)s * ND);
    const uint4* hd4 = reinterpret_cast<const uint4*>(h + (size_t)d * ND);
    float v[8];
#pragma unroll
    for (int q = 0; q < 4; ++q) { cvt8(hs4[q], v); acc8(v, &sW[(q * 8) * ED], acc); }
#pragma unroll
    for (int q = 0; q < 4; ++q) { cvt8(hd4[q], v); acc8(v, &sW[(ND + q * 8) * ED], acc); }
    float ein[ED];
    if (FIRST) {
      float a = __int_as_float(sd.z);
#pragma unroll
      for (int j = 0; j < ED; ++j) ein[j] = fmaf(a, sWe[j], sbe[j]);
    } else {
      uint4 ev = *reinterpret_cast<const uint4*>(e + (size_t)i * ED);
      cvt8(ev, ein);
    }
    acc8(ein, &sW[2 * ND * ED], acc);
#pragma unroll
    for (int j = 0; j < ED; ++j) acc[j] = fmaxf(acc[j], 0.0f);
    // residual: e_out = e_in + new_e (bf16)
    uint4 eo;
    eo.x = pack2(ein[0] + acc[0], ein[1] + acc[1]);
    eo.y = pack2(ein[2] + acc[2], ein[3] + acc[3]);
    eo.z = pack2(ein[4] + acc[4], ein[5] + acc[5]);
    eo.w = pack2(ein[6] + acc[6], ein[7] + acc[7]);
    *reinterpret_cast<uint4*>(e + (size_t)i * ED) = eo;
  } else {
#pragma unroll
    for (int j = 0; j < ED; ++j) acc[j] = 0.0f;
  }
  // wave-level segmented inclusive scan by dst (segments contiguous)
#pragma unroll
  for (int off = 1; off < 64; off <<= 1) {
    int dup = __shfl_up(d, off, 64);
    bool same = (lane >= off) && (dup == d);
#pragma unroll
    for (int j = 0; j < ED; ++j) {
      float t = __shfl_up(acc[j], off, 64);
      if (same) acc[j] += t;
    }
  }
  int dn = __shfl_down(d, 1, 64);
  bool tail = (lane == 63) || (dn != d);
  if (valid && tail) {
    float* ag = agg + (size_t)d * ED;
#pragma unroll
    for (int j = 0; j < ED; ++j) atomicAdd(&ag[j], acc[j]);
  }
}

// node MLP: h += relu([h, agg] @ W + b); h stored bf16
__global__ void k_node(u16* __restrict__ h,
                       const float* __restrict__ agg,
                       const float* __restrict__ W,  // [(ND+ED)][ND]
                       const float* __restrict__ b,  // [ND]
                       int N) {
  __shared__ float sW[(ND + ED) * ND];
  __shared__ float sb[ND];
  for (int i = threadIdx.x; i < (ND + ED) * ND; i += blockDim.x) sW[i] = W[i];
  if (threadIdx.x < ND) sb[threadIdx.x] = b[threadIdx.x];
  __syncthreads();
  int n = blockIdx.x * blockDim.x + threadIdx.x;
  if (n >= N) return;
  float acc[ND];
#pragma unroll
  for (int j = 0; j < ND; ++j) acc[j] = sb[j];
  uint4* h4 = reinterpret_cast<uint4*>(h + (size_t)n * ND);
  float hv[ND];
#pragma unroll
  for (int q = 0; q < 4; ++q) cvt8(h4[q], &hv[q * 8]);
#pragma unroll
  for (int k = 0; k < ND; ++k)
#pragma unroll
    for (int j = 0; j < ND; ++j) acc[j] = fmaf(hv[k], sW[k * ND + j], acc[j]);
  const float4* a4 = reinterpret_cast<const float4*>(agg + (size_t)n * ED);
  float4 a0 = a4[0], a1 = a4[1];
  float av[ED] = {a0.x, a0.y, a0.z, a0.w, a1.x, a1.y, a1.z, a1.w};
#pragma unroll
  for (int k = 0; k < ED; ++k)
#pragma unroll
    for (int j = 0; j < ND; ++j) acc[j] = fmaf(av[k], sW[(ND + k) * ND + j], acc[j]);
#pragma unroll
  for (int q = 0; q < 4; ++q) {
    uint4 o;
    o.x = pack2(hv[q * 8 + 0] + fmaxf(acc[q * 8 + 0], 0.0f),
                hv[q * 8 + 1] + fmaxf(acc[q * 8 + 1], 0.0f));
    o.y = pack2(hv[q * 8 + 2] + fmaxf(acc[q * 8 + 2], 0.0f),
                hv[q * 8 + 3] + fmaxf(acc[q * 8 + 3], 0.0f));
    o.z = pack2(hv[q * 8 + 4] + fmaxf(acc[q * 8 + 4], 0.0f),
                hv[q * 8 + 5] + fmaxf(acc[q * 8 + 5], 0.0f));
    o.w = pack2(hv[q * 8 + 6] + fmaxf(acc[q * 8 + 6], 0.0f),
                hv[q * 8 + 7] + fmaxf(acc[q * 8 + 7], 0.0f));
    h4[q] = o;
  }
}

// ---------- readout ----------

__device__ __forceinline__ unsigned int enc_f32(float f) {
  unsigned int bits = __float_as_uint(f);
  return (bits & 0x80000000u) ? ~bits : (bits | 0x80000000u);
}
__device__ __forceinline__ float dec_f32(unsigned int u) {
  unsigned int bits = (u & 0x80000000u) ? (u ^ 0x80000000u) : ~u;
  return __uint_as_float(bits);
}

__global__ void k_logits(const u16* __restrict__ h,
                         const int* __restrict__ cand,
                         const int* __restrict__ batch,
                         const float* __restrict__ Wout,  // [ND]
                         const float* __restrict__ bout,  // [1]
                         float* __restrict__ logits,
                         int* __restrict__ seg,
                         unsigned int* __restrict__ mxu,  // pre-zeroed
                         int NC) {
  __shared__ float sW[ND];
  if (threadIdx.x < ND) sW[threadIdx.x] = Wout[threadIdx.x];
  __syncthreads();
  int c = blockIdx.x * blockDim.x + threadIdx.x;
  if (c >= NC) return;
  int idx = cand[c];
  const uint4* hr = reinterpret_cast<const uint4*>(h + (size_t)idx * ND);
  float acc = bout[0];
  float v[8];
#pragma unroll
  for (int q = 0; q < 4; ++q) {
    cvt8(hr[q], v);
#pragma unroll
    for (int k = 0; k < 8; ++k) acc = fmaf(v[k], sW[q * 8 + k], acc);
  }
  logits[c] = acc;
  int g = batch[idx];
  seg[c] = g;
  atomicMax(&mxu[g], enc_f32(acc));
}

__global__ void k_expsum(float* __restrict__ logits,
                         const int* __restrict__ seg,
                         const unsigned int* __restrict__ mxu,
                         float* __restrict__ sum,  // pre-zeroed
                         int NC) {
  int c = blockIdx.x * blockDim.x + threadIdx.x;
  if (c >= NC) return;
  int g = seg[c];
  float sh = logits[c] - dec_f32(mxu[g]);
  logits[c] = sh;
  atomicAdd(&sum[g], expf(sh));
}

__global__ void k_final(const float* __restrict__ shifted,
                        const int* __restrict__ seg,
                        const float* __restrict__ sum,
                        float* __restrict__ out, int NC) {
  int c = blockIdx.x * blockDim.x + threadIdx.x;
  if (c >= NC) return;
  out[c] = shifted[c] - logf(sum[seg[c]]);
}

// ---------- launch ----------

extern "C" void kernel_launch(void* const* d_in, const int* in_sizes, int n_in,
                              void* d_out, int out_size, void* d_ws, size_t ws_size,
                              hipStream_t stream) {
  const float* x       = (const float*)d_in[0];
  const float* ea      = (const float*)d_in[1];
  const float* Wn_in   = (const float*)d_in[2];
  const float* bn_in   = (const float*)d_in[3];
  const float* We_in   = (const float*)d_in[4];
  const float* be_in   = (const float*)d_in[5];
  const float* We_l    = (const float*)d_in[6];
  const float* be_l    = (const float*)d_in[7];
  const float* Wn_l    = (const float*)d_in[8];
  const float* bn_l    = (const float*)d_in[9];
  const float* Wout    = (const float*)d_in[10];
  const float* bout    = (const float*)d_in[11];
  const int* edge_index= (const int*)d_in[12];
  const int* batch     = (const int*)d_in[13];
  const int* cand      = (const int*)d_in[14];

  const int N  = in_sizes[13];
  const int E  = in_sizes[1];
  const int NC = in_sizes[14];
  const int nb = (N + SCAN_B - 1) / SCAN_B;

  char* ws = (char*)d_ws;
  int4*  sedge  = (int4*)ws;  ws += (size_t)E * sizeof(int4);
  u16*   h      = (u16*)ws;   ws += (size_t)N * ND * sizeof(u16);
  u16*   e      = (u16*)ws;   ws += (size_t)E * ED * sizeof(u16);
  float* agg    = (float*)ws; ws += (size_t)N * ED * sizeof(float);
  int*   cnt    = (int*)ws;   ws += (size_t)N * sizeof(int);
  int*   cursor = (int*)ws;   ws += (size_t)N * sizeof(int);
  int*   offs   = (int*)ws;   ws += ((size_t)N + 4) * sizeof(int);
  int*   bsum   = (int*)ws;   ws += 4096;
  float* logits = (float*)ws; ws += (size_t)NC * sizeof(float);
  int*   seg    = (int*)ws;   ws += (size_t)NC * sizeof(int);
  unsigned int* mxu = (unsigned int*)ws; ws += (size_t)NG * sizeof(unsigned int);
  float* sum    = (float*)ws; ws += (size_t)NG * sizeof(float);

  const int* srcp = edge_index;
  const int* dstp = edge_index + E;
  const int blk = 256;

  // CSR build: hist -> scan -> fused 16B-record scatter
  hipMemsetAsync(cnt, 0, (size_t)N * sizeof(int), stream);
  hipMemsetAsync(cursor, 0, (size_t)N * sizeof(int), stream);
  k_hist<<<(E + blk - 1) / blk, blk, 0, stream>>>(dstp, cnt, E);
  k_blocksum<<<nb, SCAN_B, 0, stream>>>(cnt, bsum, N);
  k_scan_bsums<<<1, 1024, 0, stream>>>(bsum, nb, offs, N);
  k_scan_local<<<nb, SCAN_B, 0, stream>>>(cnt, bsum, offs, N);
  k_scatter<<<(E + blk - 1) / blk, blk, 0, stream>>>(srcp, dstp, ea, offs, cursor,
                                                     sedge, E);

  k_init_h<<<(N + blk - 1) / blk, blk, 0, stream>>>(x, Wn_in, bn_in, h, N);

  for (int l = 0; l < NL; ++l) {
    hipMemsetAsync(agg, 0, (size_t)N * ED * sizeof(float), stream);
    if (l == 0) {
      k_edge<true><<<(E + blk - 1) / blk, blk, 0, stream>>>(
          h, e, sedge, We_l, be_l, We_in, be_in, agg, E);
    } else {
      k_edge<false><<<(E + blk - 1) / blk, blk, 0, stream>>>(
          h, e, sedge, We_l + (size_t)l * (2 * ND + ED) * ED,
          be_l + (size_t)l * ED, We_in, be_in, agg, E);
    }
    k_node<<<(N + blk - 1) / blk, blk, 0, stream>>>(
        h, agg, Wn_l + (size_t)l * (ND + ED) * ND, bn_l + (size_t)l * ND, N);
  }

  hipMemsetAsync(mxu, 0, NG * sizeof(unsigned int), stream);
  hipMemsetAsync(sum, 0, NG * sizeof(float), stream);
  k_logits<<<(NC + blk - 1) / blk, blk, 0, stream>>>(h, cand, batch, Wout, bout,
                                                     logits, seg, mxu, NC);
  k_expsum<<<(NC + blk - 1) / blk, blk, 0, stream>>>(logits, seg, mxu, sum, NC);
  k_final<<<(NC + blk - 1) / blk, blk, 0, stream>>>(logits, seg, sum,
                                                    (float*)d_out, NC);
}

// Round 5
// 551.120 us; speedup vs baseline: 1.3582x; 1.0444x over previous
//
#include <hip/hip_runtime.h>

#define ND 32
#define ED 8
#define NL 4
#define NG 1000
#define SCAN_B 512
#define NBC_MAX 512   // max coarse buckets (N/256)
#define CHUNK 8192    // edges per k_binA block

typedef unsigned short u16;

// ---------- bf16 helpers (storage bf16, compute fp32) ----------

__device__ __forceinline__ u16 f2bf(float f) {
  unsigned u = __float_as_uint(f);
  u += 0x7fffu + ((u >> 16) & 1u);  // round-to-nearest-even
  return (u16)(u >> 16);
}
__device__ __forceinline__ unsigned pack2(float a, float b) {
  return (unsigned)f2bf(a) | ((unsigned)f2bf(b) << 16);
}
__device__ __forceinline__ void cvt8(uint4 p, float* o) {
  o[0] = __uint_as_float(p.x << 16); o[1] = __uint_as_float(p.x & 0xffff0000u);
  o[2] = __uint_as_float(p.y << 16); o[3] = __uint_as_float(p.y & 0xffff0000u);
  o[4] = __uint_as_float(p.z << 16); o[5] = __uint_as_float(p.z & 0xffff0000u);
  o[6] = __uint_as_float(p.w << 16); o[7] = __uint_as_float(p.w & 0xffff0000u);
}

// ---------- init ----------

__global__ void k_init_h(const float* __restrict__ x,
                         const float* __restrict__ W,  // [2][ND]
                         const float* __restrict__ b,  // [ND]
                         u16* __restrict__ h, int N) {
  __shared__ float sW[2 * ND], sb[ND];
  for (int i = threadIdx.x; i < 2 * ND; i += blockDim.x) sW[i] = W[i];
  if (threadIdx.x < ND) sb[threadIdx.x] = b[threadIdx.x];
  __syncthreads();
  int n = blockIdx.x * blockDim.x + threadIdx.x;
  if (n >= N) return;
  float x0 = x[2 * n], x1 = x[2 * n + 1];
  float v[ND];
#pragma unroll
  for (int d = 0; d < ND; ++d) v[d] = fmaf(x0, sW[d], fmaf(x1, sW[ND + d], sb[d]));
  uint4* h4 = reinterpret_cast<uint4*>(h + (size_t)n * ND);
#pragma unroll
  for (int q = 0; q < 4; ++q) {
    uint4 o;
    o.x = pack2(v[q * 8 + 0], v[q * 8 + 1]);
    o.y = pack2(v[q * 8 + 2], v[q * 8 + 3]);
    o.z = pack2(v[q * 8 + 4], v[q * 8 + 5]);
    o.w = pack2(v[q * 8 + 6], v[q * 8 + 7]);
    h4[q] = o;
  }
}

// ---------- CSR build (counting sort by dst, two-phase binned) ----------

__global__ void k_hist(const int* __restrict__ dst, int* __restrict__ cnt, int E) {
  int i = blockIdx.x * blockDim.x + threadIdx.x;
  if (i < E) atomicAdd(&cnt[dst[i]], 1);
}

__global__ void k_blocksum(const int* __restrict__ cnt, int* __restrict__ bsum, int N) {
  __shared__ int s[SCAN_B];
  int i = blockIdx.x * SCAN_B + threadIdx.x;
  s[threadIdx.x] = (i < N) ? cnt[i] : 0;
  __syncthreads();
  for (int st = SCAN_B / 2; st > 0; st >>= 1) {
    if (threadIdx.x < (unsigned)st) s[threadIdx.x] += s[threadIdx.x + st];
    __syncthreads();
  }
  if (threadIdx.x == 0) bsum[blockIdx.x] = s[0];
}

__global__ void k_scan_bsums(int* __restrict__ bsum, int nb,
                             int* __restrict__ offsets, int N) {
  __shared__ int s[1024];
  __shared__ int tot;
  int tid = threadIdx.x;
  if (nb <= 1024) {
    for (int i = tid; i < nb; i += blockDim.x) s[i] = bsum[i];
    __syncthreads();
    if (tid == 0) {
      int run = 0;
      for (int i = 0; i < nb; ++i) { int v = s[i]; s[i] = run; run += v; }
      tot = run;
    }
    __syncthreads();
    for (int i = tid; i < nb; i += blockDim.x) bsum[i] = s[i];
    if (tid == 0) offsets[N] = tot;
  } else if (tid == 0) {
    int run = 0;
    for (int i = 0; i < nb; ++i) { int v = bsum[i]; bsum[i] = run; run += v; }
    offsets[N] = run;
  }
}

__global__ void k_scan_local(const int* __restrict__ cnt,
                             const int* __restrict__ bsum,
                             int* __restrict__ offsets, int N) {
  __shared__ int s[SCAN_B];
  int i = blockIdx.x * SCAN_B + threadIdx.x;
  int v = (i < N) ? cnt[i] : 0;
  s[threadIdx.x] = v;
  __syncthreads();
  for (int st = 1; st < SCAN_B; st <<= 1) {
    int t = (threadIdx.x >= (unsigned)st) ? s[threadIdx.x - st] : 0;
    __syncthreads();
    s[threadIdx.x] += t;
    __syncthreads();
  }
  if (i < N) offsets[i] = bsum[blockIdx.x] + s[threadIdx.x] - v;  // exclusive
}

// Phase A: coarse-bin records by dst>>8 into bucket regions (dense runs per block)
__global__ void k_binA(const int* __restrict__ src, const int* __restrict__ dst,
                       const float* __restrict__ ea,
                       const int* __restrict__ offs, int* __restrict__ cursor_c,
                       int4* __restrict__ binned, int E, int N) {
  __shared__ int lcnt[NBC_MAX];
  __shared__ int lbase[NBC_MAX];
  int nbc = (N + 255) >> 8;
  for (int b = threadIdx.x; b < nbc; b += blockDim.x) lcnt[b] = 0;
  __syncthreads();
  int e0 = blockIdx.x * CHUNK;
#pragma unroll
  for (int k = 0; k < CHUNK / 256; ++k) {
    int i = e0 + k * 256 + threadIdx.x;
    if (i < E) atomicAdd(&lcnt[dst[i] >> 8], 1);
  }
  __syncthreads();
  for (int b = threadIdx.x; b < nbc; b += blockDim.x) {
    int c = lcnt[b];
    lbase[b] = c ? (offs[b << 8] + atomicAdd(&cursor_c[b], c)) : 0;
  }
  __syncthreads();
#pragma unroll
  for (int k = 0; k < CHUNK / 256; ++k) {
    int i = e0 + k * 256 + threadIdx.x;
    if (i < E) {
      int d = dst[i];
      int pos = atomicAdd(&lbase[d >> 8], 1);
      binned[pos] = make_int4(src[i], d, __float_as_int(ea[i]), 0);
    }
  }
}

// Phase B: fine sort within each 256-node bucket (64 KB region -> L2-merged writes)
__global__ void k_binB(const int4* __restrict__ binned, const int* __restrict__ offs,
                       int4* __restrict__ sedge, int N) {
  __shared__ int cur[256];
  int node0 = blockIdx.x << 8;
  int nn = min(256, N - node0);
  for (int t = threadIdx.x; t < nn; t += blockDim.x) cur[t] = offs[node0 + t];
  __syncthreads();
  int base = offs[node0];
  int end = offs[min(node0 + 256, N)];
  for (int p = base + threadIdx.x; p < end; p += blockDim.x) {
    int4 rec = binned[p];
    int pos = atomicAdd(&cur[rec.y - node0], 1);
    sedge[pos] = rec;
  }
}

// ---------- layer kernels ----------

__device__ __forceinline__ void acc8(const float* __restrict__ v,
                                     const float* __restrict__ w,  // [8][ED]
                                     float* acc) {
#pragma unroll
  for (int k = 0; k < 8; ++k)
#pragma unroll
    for (int j = 0; j < ED; ++j) acc[j] = fmaf(v[k], w[k * ED + j], acc[j]);
}

// edge MLP + fused segment-sum into agg (dst-sorted edges, wave-segmented scan)
template <bool FIRST>
__global__ void k_edge(const u16* __restrict__ h,
                       u16* __restrict__ e,
                       const int4* __restrict__ sedge,
                       const float* __restrict__ W,  // [(2*ND+ED)][ED]
                       const float* __restrict__ b,  // [ED]
                       const float* __restrict__ We0,  // [ED] (FIRST only)
                       const float* __restrict__ be0,  // [ED] (FIRST only)
                       float* __restrict__ agg,        // [N][ED], pre-zeroed
                       int E) {
  __shared__ float sW[(2 * ND + ED) * ED];
  __shared__ float sb[ED], sWe[ED], sbe[ED];
  for (int i = threadIdx.x; i < (2 * ND + ED) * ED; i += blockDim.x) sW[i] = W[i];
  if (threadIdx.x < ED) {
    sb[threadIdx.x] = b[threadIdx.x];
    if (FIRST) {
      sWe[threadIdx.x] = We0[threadIdx.x];
      sbe[threadIdx.x] = be0[threadIdx.x];
    }
  }
  __syncthreads();
  int i = blockIdx.x * blockDim.x + threadIdx.x;
  int lane = threadIdx.x & 63;
  bool valid = i < E;
  int d = -1;
  float acc[ED];
  if (valid) {
    int4 sd = sedge[i];
    int s = sd.x;
    d = sd.y;
#pragma unroll
    for (int j = 0; j < ED; ++j) acc[j] = sb[j];
    const uint4* hs4 = reinterpret_cast<const uint4*>(h + (size_t)s * ND);
    const uint4* hd4 = reinterpret_cast<const uint4*>(h + (size_t)d * ND);
    float v[8];
#pragma unroll
    for (int q = 0; q < 4; ++q) { cvt8(hs4[q], v); acc8(v, &sW[(q * 8) * ED], acc); }
#pragma unroll
    for (int q = 0; q < 4; ++q) { cvt8(hd4[q], v); acc8(v, &sW[(ND + q * 8) * ED], acc); }
    float ein[ED];
    if (FIRST) {
      float a = __int_as_float(sd.z);
#pragma unroll
      for (int j = 0; j < ED; ++j) ein[j] = fmaf(a, sWe[j], sbe[j]);
    } else {
      uint4 ev = *reinterpret_cast<const uint4*>(e + (size_t)i * ED);
      cvt8(ev, ein);
    }
    acc8(ein, &sW[2 * ND * ED], acc);
#pragma unroll
    for (int j = 0; j < ED; ++j) acc[j] = fmaxf(acc[j], 0.0f);
    uint4 eo;
    eo.x = pack2(ein[0] + acc[0], ein[1] + acc[1]);
    eo.y = pack2(ein[2] + acc[2], ein[3] + acc[3]);
    eo.z = pack2(ein[4] + acc[4], ein[5] + acc[5]);
    eo.w = pack2(ein[6] + acc[6], ein[7] + acc[7]);
    *reinterpret_cast<uint4*>(e + (size_t)i * ED) = eo;
  } else {
#pragma unroll
    for (int j = 0; j < ED; ++j) acc[j] = 0.0f;
  }
  // wave-level segmented inclusive scan by dst (segments contiguous)
#pragma unroll
  for (int off = 1; off < 64; off <<= 1) {
    int dup = __shfl_up(d, off, 64);
    bool same = (lane >= off) && (dup == d);
#pragma unroll
    for (int j = 0; j < ED; ++j) {
      float t = __shfl_up(acc[j], off, 64);
      if (same) acc[j] += t;
    }
  }
  int dn = __shfl_down(d, 1, 64);
  bool tail = (lane == 63) || (dn != d);
  if (valid && tail) {
    float* ag = agg + (size_t)d * ED;
#pragma unroll
    for (int j = 0; j < ED; ++j) atomicAdd(&ag[j], acc[j]);
  }
}

// node MLP: h += relu([h, agg] @ W + b); h stored bf16
__global__ void k_node(u16* __restrict__ h,
                       const float* __restrict__ agg,
                       const float* __restrict__ W,  // [(ND+ED)][ND]
                       const float* __restrict__ b,  // [ND]
                       int N) {
  __shared__ float sW[(ND + ED) * ND];
  __shared__ float sb[ND];
  for (int i = threadIdx.x; i < (ND + ED) * ND; i += blockDim.x) sW[i] = W[i];
  if (threadIdx.x < ND) sb[threadIdx.x] = b[threadIdx.x];
  __syncthreads();
  int n = blockIdx.x * blockDim.x + threadIdx.x;
  if (n >= N) return;
  float acc[ND];
#pragma unroll
  for (int j = 0; j < ND; ++j) acc[j] = sb[j];
  uint4* h4 = reinterpret_cast<uint4*>(h + (size_t)n * ND);
  float hv[ND];
#pragma unroll
  for (int q = 0; q < 4; ++q) cvt8(h4[q], &hv[q * 8]);
#pragma unroll
  for (int k = 0; k < ND; ++k)
#pragma unroll
    for (int j = 0; j < ND; ++j) acc[j] = fmaf(hv[k], sW[k * ND + j], acc[j]);
  const float4* a4 = reinterpret_cast<const float4*>(agg + (size_t)n * ED);
  float4 a0 = a4[0], a1 = a4[1];
  float av[ED] = {a0.x, a0.y, a0.z, a0.w, a1.x, a1.y, a1.z, a1.w};
#pragma unroll
  for (int k = 0; k < ED; ++k)
#pragma unroll
    for (int j = 0; j < ND; ++j) acc[j] = fmaf(av[k], sW[(ND + k) * ND + j], acc[j]);
#pragma unroll
  for (int q = 0; q < 4; ++q) {
    uint4 o;
    o.x = pack2(hv[q * 8 + 0] + fmaxf(acc[q * 8 + 0], 0.0f),
                hv[q * 8 + 1] + fmaxf(acc[q * 8 + 1], 0.0f));
    o.y = pack2(hv[q * 8 + 2] + fmaxf(acc[q * 8 + 2], 0.0f),
                hv[q * 8 + 3] + fmaxf(acc[q * 8 + 3], 0.0f));
    o.z = pack2(hv[q * 8 + 4] + fmaxf(acc[q * 8 + 4], 0.0f),
                hv[q * 8 + 5] + fmaxf(acc[q * 8 + 5], 0.0f));
    o.w = pack2(hv[q * 8 + 6] + fmaxf(acc[q * 8 + 6], 0.0f),
                hv[q * 8 + 7] + fmaxf(acc[q * 8 + 7], 0.0f));
    h4[q] = o;
  }
}

// ---------- readout ----------

__device__ __forceinline__ unsigned int enc_f32(float f) {
  unsigned int bits = __float_as_uint(f);
  return (bits & 0x80000000u) ? ~bits : (bits | 0x80000000u);
}
__device__ __forceinline__ float dec_f32(unsigned int u) {
  unsigned int bits = (u & 0x80000000u) ? (u ^ 0x80000000u) : ~u;
  return __uint_as_float(bits);
}

__global__ void k_logits(const u16* __restrict__ h,
                         const int* __restrict__ cand,
                         const int* __restrict__ batch,
                         const float* __restrict__ Wout,  // [ND]
                         const float* __restrict__ bout,  // [1]
                         float* __restrict__ logits,
                         int* __restrict__ seg,
                         unsigned int* __restrict__ mxu,  // pre-zeroed
                         int NC) {
  __shared__ float sW[ND];
  if (threadIdx.x < ND) sW[threadIdx.x] = Wout[threadIdx.x];
  __syncthreads();
  int c = blockIdx.x * blockDim.x + threadIdx.x;
  if (c >= NC) return;
  int idx = cand[c];
  const uint4* hr = reinterpret_cast<const uint4*>(h + (size_t)idx * ND);
  float acc = bout[0];
  float v[8];
#pragma unroll
  for (int q = 0; q < 4; ++q) {
    cvt8(hr[q], v);
#pragma unroll
    for (int k = 0; k < 8; ++k) acc = fmaf(v[k], sW[q * 8 + k], acc);
  }
  logits[c] = acc;
  int g = batch[idx];
  seg[c] = g;
  atomicMax(&mxu[g], enc_f32(acc));
}

__global__ void k_expsum(float* __restrict__ logits,
                         const int* __restrict__ seg,
                         const unsigned int* __restrict__ mxu,
                         float* __restrict__ sum,  // pre-zeroed
                         int NC) {
  int c = blockIdx.x * blockDim.x + threadIdx.x;
  if (c >= NC) return;
  int g = seg[c];
  float sh = logits[c] - dec_f32(mxu[g]);
  logits[c] = sh;
  atomicAdd(&sum[g], expf(sh));
}

__global__ void k_final(const float* __restrict__ shifted,
                        const int* __restrict__ seg,
                        const float* __restrict__ sum,
                        float* __restrict__ out, int NC) {
  int c = blockIdx.x * blockDim.x + threadIdx.x;
  if (c >= NC) return;
  out[c] = shifted[c] - logf(sum[seg[c]]);
}

// ---------- launch ----------

extern "C" void kernel_launch(void* const* d_in, const int* in_sizes, int n_in,
                              void* d_out, int out_size, void* d_ws, size_t ws_size,
                              hipStream_t stream) {
  const float* x       = (const float*)d_in[0];
  const float* ea      = (const float*)d_in[1];
  const float* Wn_in   = (const float*)d_in[2];
  const float* bn_in   = (const float*)d_in[3];
  const float* We_in   = (const float*)d_in[4];
  const float* be_in   = (const float*)d_in[5];
  const float* We_l    = (const float*)d_in[6];
  const float* be_l    = (const float*)d_in[7];
  const float* Wn_l    = (const float*)d_in[8];
  const float* bn_l    = (const float*)d_in[9];
  const float* Wout    = (const float*)d_in[10];
  const float* bout    = (const float*)d_in[11];
  const int* edge_index= (const int*)d_in[12];
  const int* batch     = (const int*)d_in[13];
  const int* cand      = (const int*)d_in[14];

  const int N  = in_sizes[13];
  const int E  = in_sizes[1];
  const int NC = in_sizes[14];
  const int nb = (N + SCAN_B - 1) / SCAN_B;
  const int nbc = (N + 255) >> 8;

  char* ws = (char*)d_ws;
  int4*  sedge  = (int4*)ws;  ws += (size_t)E * sizeof(int4);
  int4*  binned = (int4*)ws;  ws += (size_t)E * sizeof(int4);
  u16*   h      = (u16*)ws;   ws += (size_t)N * ND * sizeof(u16);
  u16*   e      = (u16*)ws;   ws += (size_t)E * ED * sizeof(u16);
  float* agg    = (float*)ws; ws += (size_t)N * ED * sizeof(float);
  int*   cnt    = (int*)ws;   ws += (size_t)N * sizeof(int);
  int*   cursor = (int*)ws;   ws += (size_t)N * sizeof(int);
  int*   offs   = (int*)ws;   ws += ((size_t)N + 4) * sizeof(int);
  int*   bsum   = (int*)ws;   ws += 4096;
  float* logits = (float*)ws; ws += (size_t)NC * sizeof(float);
  int*   seg    = (int*)ws;   ws += (size_t)NC * sizeof(int);
  unsigned int* mxu = (unsigned int*)ws; ws += (size_t)NG * sizeof(unsigned int);
  float* sum    = (float*)ws; ws += (size_t)NG * sizeof(float);

  const int* srcp = edge_index;
  const int* dstp = edge_index + E;
  const int blk = 256;

  // CSR build: hist -> scan -> binned two-phase counting sort
  hipMemsetAsync(cnt, 0, (size_t)N * sizeof(int), stream);
  hipMemsetAsync(cursor, 0, (size_t)nbc * sizeof(int), stream);
  k_hist<<<(E + blk - 1) / blk, blk, 0, stream>>>(dstp, cnt, E);
  k_blocksum<<<nb, SCAN_B, 0, stream>>>(cnt, bsum, N);
  k_scan_bsums<<<1, 1024, 0, stream>>>(bsum, nb, offs, N);
  k_scan_local<<<nb, SCAN_B, 0, stream>>>(cnt, bsum, offs, N);
  k_binA<<<(E + CHUNK - 1) / CHUNK, blk, 0, stream>>>(srcp, dstp, ea, offs, cursor,
                                                      binned, E, N);
  k_binB<<<nbc, blk, 0, stream>>>(binned, offs, sedge, N);

  k_init_h<<<(N + blk - 1) / blk, blk, 0, stream>>>(x, Wn_in, bn_in, h, N);

  for (int l = 0; l < NL; ++l) {
    hipMemsetAsync(agg, 0, (size_t)N * ED * sizeof(float), stream);
    if (l == 0) {
      k_edge<true><<<(E + blk - 1) / blk, blk, 0, stream>>>(
          h, e, sedge, We_l, be_l, We_in, be_in, agg, E);
    } else {
      k_edge<false><<<(E + blk - 1) / blk, blk, 0, stream>>>(
          h, e, sedge, We_l + (size_t)l * (2 * ND + ED) * ED,
          be_l + (size_t)l * ED, We_in, be_in, agg, E);
    }
    k_node<<<(N + blk - 1) / blk, blk, 0, stream>>>(
        h, agg, Wn_l + (size_t)l * (ND + ED) * ND, bn_l + (size_t)l * ND, N);
  }

  hipMemsetAsync(mxu, 0, NG * sizeof(unsigned int), stream);
  hipMemsetAsync(sum, 0, NG * sizeof(float), stream);
  k_logits<<<(NC + blk - 1) / blk, blk, 0, stream>>>(h, cand, batch, Wout, bout,
                                                     logits, seg, mxu, NC);
  k_expsum<<<(NC + blk - 1) / blk, blk, 0, stream>>>(logits, seg, mxu, sum, NC);
  k_final<<<(NC + blk - 1) / blk, blk, 0, stream>>>(logits, seg, sum,
                                                    (float*)d_out, NC);
}

// Round 6
// 514.036 us; speedup vs baseline: 1.4562x; 1.0721x over previous
//
#include <hip/hip_runtime.h>

#define ND 32
#define ED 8
#define NL 4
#define NG 1000
#define NBC_MAX 512   // max coarse buckets (N/256)
#define CHUNK 8192    // edges per k_binA block
#define CHUNK_H 32768 // edges per k_chist block

typedef unsigned short u16;

// ---------- bf16 helpers (storage bf16, compute fp32) ----------

__device__ __forceinline__ u16 f2bf(float f) {
  unsigned u = __float_as_uint(f);
  u += 0x7fffu + ((u >> 16) & 1u);  // round-to-nearest-even
  return (u16)(u >> 16);
}
__device__ __forceinline__ unsigned pack2(float a, float b) {
  return (unsigned)f2bf(a) | ((unsigned)f2bf(b) << 16);
}
__device__ __forceinline__ void cvt8(uint4 p, float* o) {
  o[0] = __uint_as_float(p.x << 16); o[1] = __uint_as_float(p.x & 0xffff0000u);
  o[2] = __uint_as_float(p.y << 16); o[3] = __uint_as_float(p.y & 0xffff0000u);
  o[4] = __uint_as_float(p.z << 16); o[5] = __uint_as_float(p.z & 0xffff0000u);
  o[6] = __uint_as_float(p.w << 16); o[7] = __uint_as_float(p.w & 0xffff0000u);
}

// ---------- init ----------

__global__ void k_init_h(const float* __restrict__ x,
                         const float* __restrict__ W,  // [2][ND]
                         const float* __restrict__ b,  // [ND]
                         u16* __restrict__ h, int N) {
  __shared__ float sW[2 * ND], sb[ND];
  for (int i = threadIdx.x; i < 2 * ND; i += blockDim.x) sW[i] = W[i];
  if (threadIdx.x < ND) sb[threadIdx.x] = b[threadIdx.x];
  __syncthreads();
  int n = blockIdx.x * blockDim.x + threadIdx.x;
  if (n >= N) return;
  float x0 = x[2 * n], x1 = x[2 * n + 1];
  float v[ND];
#pragma unroll
  for (int d = 0; d < ND; ++d) v[d] = fmaf(x0, sW[d], fmaf(x1, sW[ND + d], sb[d]));
  uint4* h4 = reinterpret_cast<uint4*>(h + (size_t)n * ND);
#pragma unroll
  for (int q = 0; q < 4; ++q) {
    uint4 o;
    o.x = pack2(v[q * 8 + 0], v[q * 8 + 1]);
    o.y = pack2(v[q * 8 + 2], v[q * 8 + 3]);
    o.z = pack2(v[q * 8 + 4], v[q * 8 + 5]);
    o.w = pack2(v[q * 8 + 6], v[q * 8 + 7]);
    h4[q] = o;
  }
}

// ---------- CSR-free binned counting sort by dst ----------

// coarse histogram over 256-node buckets; LDS-local, few global atomics
__global__ void k_chist(const int* __restrict__ dst, int* __restrict__ bcnt,
                        int E, int nbc) {
  __shared__ int lcnt[NBC_MAX];
  for (int b = threadIdx.x; b < nbc; b += blockDim.x) lcnt[b] = 0;
  __syncthreads();
  int e0 = blockIdx.x * CHUNK_H;
  int e1 = min(e0 + CHUNK_H, E);
  for (int i = e0 + threadIdx.x; i < e1; i += blockDim.x)
    atomicAdd(&lcnt[dst[i] >> 8], 1);
  __syncthreads();
  for (int b = threadIdx.x; b < nbc; b += blockDim.x)
    if (lcnt[b]) atomicAdd(&bcnt[b], lcnt[b]);
}

// exclusive scan of bucket counts -> bbase[0..nbc] (bbase[nbc] = E)
__global__ void k_cscan(const int* __restrict__ bcnt, int* __restrict__ bbase,
                        int nbc) {
  __shared__ int s[NBC_MAX];
  int tid = threadIdx.x;
  if (nbc <= NBC_MAX) {
    int v = (tid < nbc) ? bcnt[tid] : 0;
    s[tid] = v;
    __syncthreads();
    for (int st = 1; st < NBC_MAX; st <<= 1) {
      int t = (tid >= st) ? s[tid - st] : 0;
      __syncthreads();
      s[tid] += t;
      __syncthreads();
    }
    if (tid < nbc) bbase[tid] = s[tid] - v;
    if (tid == nbc - 1) bbase[nbc] = s[tid];
  } else if (tid == 0) {
    int run = 0;
    for (int i = 0; i < nbc; ++i) { bbase[i] = run; run += bcnt[i]; }
    bbase[nbc] = run;
  }
}

// Phase A: coarse-bin 16B records by dst>>8 into bucket regions (dense runs)
__global__ void k_binA(const int* __restrict__ src, const int* __restrict__ dst,
                       const float* __restrict__ ea,
                       const int* __restrict__ bbase, int* __restrict__ cursor_c,
                       int4* __restrict__ binned, int E, int nbc) {
  __shared__ int lcnt[NBC_MAX];
  __shared__ int lbase[NBC_MAX];
  for (int b = threadIdx.x; b < nbc; b += blockDim.x) lcnt[b] = 0;
  __syncthreads();
  int e0 = blockIdx.x * CHUNK;
#pragma unroll
  for (int k = 0; k < CHUNK / 256; ++k) {
    int i = e0 + k * 256 + threadIdx.x;
    if (i < E) atomicAdd(&lcnt[dst[i] >> 8], 1);
  }
  __syncthreads();
  for (int b = threadIdx.x; b < nbc; b += blockDim.x) {
    int c = lcnt[b];
    lbase[b] = c ? (bbase[b] + atomicAdd(&cursor_c[b], c)) : 0;
  }
  __syncthreads();
#pragma unroll
  for (int k = 0; k < CHUNK / 256; ++k) {
    int i = e0 + k * 256 + threadIdx.x;
    if (i < E) {
      int d = dst[i];
      int pos = atomicAdd(&lbase[d >> 8], 1);
      binned[pos] = make_int4(src[i], d, __float_as_int(ea[i]), 0);
    }
  }
}

// Phase B: fine sort within each 256-node bucket; per-node hist+scan in LDS,
// scattered writes confined to a 64 KB region (L2-merged)
__global__ void k_binB(const int4* __restrict__ binned,
                       const int* __restrict__ bbase,
                       int4* __restrict__ sedge, int N) {
  __shared__ int hist[256];
  __shared__ int scn[256];
  int b = blockIdx.x;
  int base = bbase[b], end = bbase[b + 1];
  hist[threadIdx.x] = 0;
  __syncthreads();
  for (int p = base + threadIdx.x; p < end; p += blockDim.x)
    atomicAdd(&hist[binned[p].y & 255], 1);
  __syncthreads();
  int v = hist[threadIdx.x];
  scn[threadIdx.x] = v;
  __syncthreads();
  for (int st = 1; st < 256; st <<= 1) {
    int t = (threadIdx.x >= (unsigned)st) ? scn[threadIdx.x - st] : 0;
    __syncthreads();
    scn[threadIdx.x] += t;
    __syncthreads();
  }
  hist[threadIdx.x] = base + scn[threadIdx.x] - v;  // exclusive cursor
  __syncthreads();
  for (int p = base + threadIdx.x; p < end; p += blockDim.x) {
    int4 rec = binned[p];  // L2-hot (same 64KB read twice)
    int pos = atomicAdd(&hist[rec.y & 255], 1);
    sedge[pos] = rec;
  }
}

// ---------- layer kernels ----------

__device__ __forceinline__ void acc8(const float* __restrict__ v,
                                     const float* __restrict__ w,  // [8][ED]
                                     float* acc) {
#pragma unroll
  for (int k = 0; k < 8; ++k)
#pragma unroll
    for (int j = 0; j < ED; ++j) acc[j] = fmaf(v[k], w[k * ED + j], acc[j]);
}

// edge MLP + fused segment-sum into agg (dst-sorted edges, wave-segmented scan)
template <bool FIRST>
__global__ void k_edge(const u16* __restrict__ h,
                       u16* __restrict__ e,
                       const int4* __restrict__ sedge,
                       const float* __restrict__ W,  // [(2*ND+ED)][ED]
                       const float* __restrict__ b,  // [ED]
                       const float* __restrict__ We0,  // [ED] (FIRST only)
                       const float* __restrict__ be0,  // [ED] (FIRST only)
                       float* __restrict__ agg,        // [N][ED], pre-zeroed
                       int E) {
  __shared__ float sW[(2 * ND + ED) * ED];
  __shared__ float sb[ED], sWe[ED], sbe[ED];
  for (int i = threadIdx.x; i < (2 * ND + ED) * ED; i += blockDim.x) sW[i] = W[i];
  if (threadIdx.x < ED) {
    sb[threadIdx.x] = b[threadIdx.x];
    if (FIRST) {
      sWe[threadIdx.x] = We0[threadIdx.x];
      sbe[threadIdx.x] = be0[threadIdx.x];
    }
  }
  __syncthreads();
  int i = blockIdx.x * blockDim.x + threadIdx.x;
  int lane = threadIdx.x & 63;
  bool valid = i < E;
  int d = -1;
  float acc[ED];
  if (valid) {
    int4 sd = sedge[i];
    int s = sd.x;
    d = sd.y;
#pragma unroll
    for (int j = 0; j < ED; ++j) acc[j] = sb[j];
    const uint4* hs4 = reinterpret_cast<const uint4*>(h + (size_t)s * ND);
    const uint4* hd4 = reinterpret_cast<const uint4*>(h + (size_t)d * ND);
    float v[8];
#pragma unroll
    for (int q = 0; q < 4; ++q) { cvt8(hs4[q], v); acc8(v, &sW[(q * 8) * ED], acc); }
#pragma unroll
    for (int q = 0; q < 4; ++q) { cvt8(hd4[q], v); acc8(v, &sW[(ND + q * 8) * ED], acc); }
    float ein[ED];
    if (FIRST) {
      float a = __int_as_float(sd.z);
#pragma unroll
      for (int j = 0; j < ED; ++j) ein[j] = fmaf(a, sWe[j], sbe[j]);
    } else {
      uint4 ev = *reinterpret_cast<const uint4*>(e + (size_t)i * ED);
      cvt8(ev, ein);
    }
    acc8(ein, &sW[2 * ND * ED], acc);
#pragma unroll
    for (int j = 0; j < ED; ++j) acc[j] = fmaxf(acc[j], 0.0f);
    uint4 eo;
    eo.x = pack2(ein[0] + acc[0], ein[1] + acc[1]);
    eo.y = pack2(ein[2] + acc[2], ein[3] + acc[3]);
    eo.z = pack2(ein[4] + acc[4], ein[5] + acc[5]);
    eo.w = pack2(ein[6] + acc[6], ein[7] + acc[7]);
    *reinterpret_cast<uint4*>(e + (size_t)i * ED) = eo;
  } else {
#pragma unroll
    for (int j = 0; j < ED; ++j) acc[j] = 0.0f;
  }
  // wave-level segmented inclusive scan by dst (segments contiguous)
#pragma unroll
  for (int off = 1; off < 64; off <<= 1) {
    int dup = __shfl_up(d, off, 64);
    bool same = (lane >= off) && (dup == d);
#pragma unroll
    for (int j = 0; j < ED; ++j) {
      float t = __shfl_up(acc[j], off, 64);
      if (same) acc[j] += t;
    }
  }
  int dn = __shfl_down(d, 1, 64);
  bool tail = (lane == 63) || (dn != d);
  if (valid && tail) {
    float* ag = agg + (size_t)d * ED;
#pragma unroll
    for (int j = 0; j < ED; ++j) atomicAdd(&ag[j], acc[j]);
  }
}

// node MLP: h += relu([h, agg] @ W + b); h stored bf16
__global__ void k_node(u16* __restrict__ h,
                       const float* __restrict__ agg,
                       const float* __restrict__ W,  // [(ND+ED)][ND]
                       const float* __restrict__ b,  // [ND]
                       int N) {
  __shared__ float sW[(ND + ED) * ND];
  __shared__ float sb[ND];
  for (int i = threadIdx.x; i < (ND + ED) * ND; i += blockDim.x) sW[i] = W[i];
  if (threadIdx.x < ND) sb[threadIdx.x] = b[threadIdx.x];
  __syncthreads();
  int n = blockIdx.x * blockDim.x + threadIdx.x;
  if (n >= N) return;
  float acc[ND];
#pragma unroll
  for (int j = 0; j < ND; ++j) acc[j] = sb[j];
  uint4* h4 = reinterpret_cast<uint4*>(h + (size_t)n * ND);
  float hv[ND];
#pragma unroll
  for (int q = 0; q < 4; ++q) cvt8(h4[q], &hv[q * 8]);
#pragma unroll
  for (int k = 0; k < ND; ++k)
#pragma unroll
    for (int j = 0; j < ND; ++j) acc[j] = fmaf(hv[k], sW[k * ND + j], acc[j]);
  const float4* a4 = reinterpret_cast<const float4*>(agg + (size_t)n * ED);
  float4 a0 = a4[0], a1 = a4[1];
  float av[ED] = {a0.x, a0.y, a0.z, a0.w, a1.x, a1.y, a1.z, a1.w};
#pragma unroll
  for (int k = 0; k < ED; ++k)
#pragma unroll
    for (int j = 0; j < ND; ++j) acc[j] = fmaf(av[k], sW[(ND + k) * ND + j], acc[j]);
#pragma unroll
  for (int q = 0; q < 4; ++q) {
    uint4 o;
    o.x = pack2(hv[q * 8 + 0] + fmaxf(acc[q * 8 + 0], 0.0f),
                hv[q * 8 + 1] + fmaxf(acc[q * 8 + 1], 0.0f));
    o.y = pack2(hv[q * 8 + 2] + fmaxf(acc[q * 8 + 2], 0.0f),
                hv[q * 8 + 3] + fmaxf(acc[q * 8 + 3], 0.0f));
    o.z = pack2(hv[q * 8 + 4] + fmaxf(acc[q * 8 + 4], 0.0f),
                hv[q * 8 + 5] + fmaxf(acc[q * 8 + 5], 0.0f));
    o.w = pack2(hv[q * 8 + 6] + fmaxf(acc[q * 8 + 6], 0.0f),
                hv[q * 8 + 7] + fmaxf(acc[q * 8 + 7], 0.0f));
    h4[q] = o;
  }
}

// ---------- readout ----------

__device__ __forceinline__ unsigned int enc_f32(float f) {
  unsigned int bits = __float_as_uint(f);
  return (bits & 0x80000000u) ? ~bits : (bits | 0x80000000u);
}
__device__ __forceinline__ float dec_f32(unsigned int u) {
  unsigned int bits = (u & 0x80000000u) ? (u ^ 0x80000000u) : ~u;
  return __uint_as_float(bits);
}

__global__ void k_logits(const u16* __restrict__ h,
                         const int* __restrict__ cand,
                         const int* __restrict__ batch,
                         const float* __restrict__ Wout,  // [ND]
                         const float* __restrict__ bout,  // [1]
                         float* __restrict__ logits,
                         int* __restrict__ seg,
                         unsigned int* __restrict__ mxu,  // pre-zeroed
                         int NC) {
  __shared__ float sW[ND];
  if (threadIdx.x < ND) sW[threadIdx.x] = Wout[threadIdx.x];
  __syncthreads();
  int c = blockIdx.x * blockDim.x + threadIdx.x;
  if (c >= NC) return;
  int idx = cand[c];
  const uint4* hr = reinterpret_cast<const uint4*>(h + (size_t)idx * ND);
  float acc = bout[0];
  float v[8];
#pragma unroll
  for (int q = 0; q < 4; ++q) {
    cvt8(hr[q], v);
#pragma unroll
    for (int k = 0; k < 8; ++k) acc = fmaf(v[k], sW[q * 8 + k], acc);
  }
  logits[c] = acc;
  int g = batch[idx];
  seg[c] = g;
  atomicMax(&mxu[g], enc_f32(acc));
}

__global__ void k_expsum(float* __restrict__ logits,
                         const int* __restrict__ seg,
                         const unsigned int* __restrict__ mxu,
                         float* __restrict__ sum,  // pre-zeroed
                         int NC) {
  int c = blockIdx.x * blockDim.x + threadIdx.x;
  if (c >= NC) return;
  int g = seg[c];
  float sh = logits[c] - dec_f32(mxu[g]);
  logits[c] = sh;
  atomicAdd(&sum[g], expf(sh));
}

__global__ void k_final(const float* __restrict__ shifted,
                        const int* __restrict__ seg,
                        const float* __restrict__ sum,
                        float* __restrict__ out, int NC) {
  int c = blockIdx.x * blockDim.x + threadIdx.x;
  if (c >= NC) return;
  out[c] = shifted[c] - logf(sum[seg[c]]);
}

// ---------- launch ----------

extern "C" void kernel_launch(void* const* d_in, const int* in_sizes, int n_in,
                              void* d_out, int out_size, void* d_ws, size_t ws_size,
                              hipStream_t stream) {
  const float* x       = (const float*)d_in[0];
  const float* ea      = (const float*)d_in[1];
  const float* Wn_in   = (const float*)d_in[2];
  const float* bn_in   = (const float*)d_in[3];
  const float* We_in   = (const float*)d_in[4];
  const float* be_in   = (const float*)d_in[5];
  const float* We_l    = (const float*)d_in[6];
  const float* be_l    = (const float*)d_in[7];
  const float* Wn_l    = (const float*)d_in[8];
  const float* bn_l    = (const float*)d_in[9];
  const float* Wout    = (const float*)d_in[10];
  const float* bout    = (const float*)d_in[11];
  const int* edge_index= (const int*)d_in[12];
  const int* batch     = (const int*)d_in[13];
  const int* cand      = (const int*)d_in[14];

  const int N  = in_sizes[13];
  const int E  = in_sizes[1];
  const int NC = in_sizes[14];
  const int nbc = (N + 255) >> 8;

  char* ws = (char*)d_ws;
  int4*  sedge  = (int4*)ws;  ws += (size_t)E * sizeof(int4);
  int4*  binned = (int4*)ws;  ws += (size_t)E * sizeof(int4);
  u16*   h      = (u16*)ws;   ws += (size_t)N * ND * sizeof(u16);
  u16*   e      = (u16*)ws;   ws += (size_t)E * ED * sizeof(u16);
  float* agg    = (float*)ws; ws += (size_t)N * ED * sizeof(float);
  int*   bcnt   = (int*)ws;   ws += (size_t)NBC_MAX * sizeof(int);
  int*   cursor = (int*)ws;   ws += (size_t)NBC_MAX * sizeof(int);
  int*   bbase  = (int*)ws;   ws += ((size_t)NBC_MAX + 4) * sizeof(int);
  float* logits = (float*)ws; ws += (size_t)NC * sizeof(float);
  int*   seg    = (int*)ws;   ws += (size_t)NC * sizeof(int);
  unsigned int* mxu = (unsigned int*)ws; ws += (size_t)NG * sizeof(unsigned int);
  float* sum    = (float*)ws; ws += (size_t)NG * sizeof(float);

  const int* srcp = edge_index;
  const int* dstp = edge_index + E;
  const int blk = 256;

  // binned two-phase counting sort (no per-node global histogram/scan)
  hipMemsetAsync(bcnt, 0, (size_t)NBC_MAX * sizeof(int), stream);
  hipMemsetAsync(cursor, 0, (size_t)NBC_MAX * sizeof(int), stream);
  k_chist<<<(E + CHUNK_H - 1) / CHUNK_H, blk, 0, stream>>>(dstp, bcnt, E, nbc);
  k_cscan<<<1, NBC_MAX, 0, stream>>>(bcnt, bbase, nbc);
  k_binA<<<(E + CHUNK - 1) / CHUNK, blk, 0, stream>>>(srcp, dstp, ea, bbase, cursor,
                                                      binned, E, nbc);
  k_binB<<<nbc, 256, 0, stream>>>(binned, bbase, sedge, N);

  k_init_h<<<(N + blk - 1) / blk, blk, 0, stream>>>(x, Wn_in, bn_in, h, N);

  for (int l = 0; l < NL; ++l) {
    hipMemsetAsync(agg, 0, (size_t)N * ED * sizeof(float), stream);
    if (l == 0) {
      k_edge<true><<<(E + blk - 1) / blk, blk, 0, stream>>>(
          h, e, sedge, We_l, be_l, We_in, be_in, agg, E);
    } else {
      k_edge<false><<<(E + blk - 1) / blk, blk, 0, stream>>>(
          h, e, sedge, We_l + (size_t)l * (2 * ND + ED) * ED,
          be_l + (size_t)l * ED, We_in, be_in, agg, E);
    }
    k_node<<<(N + blk - 1) / blk, blk, 0, stream>>>(
        h, agg, Wn_l + (size_t)l * (ND + ED) * ND, bn_l + (size_t)l * ND, N);
  }

  hipMemsetAsync(mxu, 0, NG * sizeof(unsigned int), stream);
  hipMemsetAsync(sum, 0, NG * sizeof(float), stream);
  k_logits<<<(NC + blk - 1) / blk, blk, 0, stream>>>(h, cand, batch, Wout, bout,
                                                     logits, seg, mxu, NC);
  k_expsum<<<(NC + blk - 1) / blk, blk, 0, stream>>>(logits, seg, mxu, sum, NC);
  k_final<<<(NC + blk - 1) / blk, blk, 0, stream>>>(logits, seg, sum,
                                                    (float*)d_out, NC);
}